// Round 17
// baseline (275.851 us; speedup 1.0000x reference)
//
#include <hip/hip_runtime.h>
#include <hip/hip_bf16.h>

#define HIDDEN 128
#define NI_N 100000
#define NT_N 100000
#define NE_N 800000
#define EPS_F 1e-5f
#define ELLW 32
#define ACC_REP 128           // accum replicas: 12500 agg blocks / 128 ~= 98
                              // same-XCD contenders per address (128 % 8 == 0)

// k_main block layout: [0,NB_PROJ) proj, [NB_PROJ,NB_PROJ+NB_SC) scatter.
// (adst role moved into k_agg's prologue in r17 — half-wave = one row.)
#define NB_PROJ 782
#define NB_SC 512
#define SC_THREADS (NB_SC * 256)
#define SC_K 7                // 512*256*7 >= 800000
// k_pre block layout
#define NB_ZERO 391           // 391*256 >= 100000

typedef __attribute__((ext_vector_type(8))) short bf16x8;
typedef __attribute__((ext_vector_type(4))) float f32x4;

static __device__ __forceinline__ unsigned short f2bf(float f) {
  unsigned u = __float_as_uint(f);
  u += 0x7FFFu + ((u >> 16) & 1u);  // round-to-nearest-even
  return (unsigned short)(u >> 16);
}

static __device__ __forceinline__ bf16x8 pack8(float4 a, float4 b) {
  bf16x8 r;
  r[0] = (short)f2bf(a.x); r[1] = (short)f2bf(a.y);
  r[2] = (short)f2bf(a.z); r[3] = (short)f2bf(a.w);
  r[4] = (short)f2bf(b.x); r[5] = (short)f2bf(b.y);
  r[6] = (short)f2bf(b.z); r[7] = (short)f2bf(b.w);
  return r;
}

static __device__ __forceinline__ float bf_lo(unsigned int h) {
  return __uint_as_float(h << 16);
}
static __device__ __forceinline__ float bf_hi(unsigned int h) {
  return __uint_as_float(h & 0xffff0000u);
}

// permuted-layout column mapping: uint index p holds true cols c0(p) [lo16]
// and c0(p)+16 [hi16], where c0 = (p>>5)*64 + ((p>>4)&1)*32 + (p&15).

// ---------------------------------------------------------------------------
// k_pre: blocks [0,391) zero the ELL cursor; block 391 computes
// weff[k] = sum_c att_dst[c]*W_taste[c,k], beff = att.b into wbuf, and
// zeroes the 128-replica stats accumulator.
// ---------------------------------------------------------------------------
__global__ __launch_bounds__(256) void k_pre(const float* __restrict__ W,
                                             const float* __restrict__ b,
                                             const float* __restrict__ att,
                                             float* __restrict__ wbuf,
                                             int* __restrict__ cursor,
                                             float* __restrict__ accum) {
  int bid = blockIdx.x, t = threadIdx.x;
  if (bid < NB_ZERO) {
    int i = bid * 256 + t;
    if (i < NT_N) cursor[i] = 0;
    return;
  }
  __shared__ float red[128];
#pragma unroll 8
  for (int r = 0; r < ACC_REP; ++r) accum[r * 256 + t] = 0.f;
  if (t < 128) {
    float s = 0.f;
#pragma unroll 8
    for (int c = 0; c < 128; ++c) s += att[c] * W[c * 128 + t];
    wbuf[t] = s;
    red[t] = att[t] * b[t];
  }
  __syncthreads();
  if (t < 64) {
    float v = red[t] + red[t + 64];
    v += __shfl_xor(v, 1);
    v += __shfl_xor(v, 2);
    v += __shfl_xor(v, 4);
    v += __shfl_xor(v, 8);
    v += __shfl_xor(v, 16);
    v += __shfl_xor(v, 32);
    if (t == 0) wbuf[128] = v;
  }
}

// ---------------------------------------------------------------------------
// k_main: proj + scatter only (adst moved to k_agg's prologue — its
// half-wave/node layout reads one x_taste row as 32 coalesced float4s).
// Proj/scatter bodies byte-identical to the proven r7 forms. Kept
// standalone: proj needs 104 VGPR (r4/r9/r10: never co-compile with
// low-VGPR phases, never clamp).
// ---------------------------------------------------------------------------
__global__ __launch_bounds__(256) void k_main(
    const float* __restrict__ x, const float* __restrict__ W,
    const float* __restrict__ bias, const float* __restrict__ att,
    unsigned int* __restrict__ h32, float* __restrict__ a_src,
    const int* __restrict__ esrc, const int* __restrict__ edst,
    int* __restrict__ cursor, int* __restrict__ ell) {
  const int t = threadIdx.x;

  if (blockIdx.x >= NB_PROJ) {
    // ---- scatter role: 7 edges per thread, phase-split for MLP ----
    int base = (blockIdx.x - NB_PROJ) * 256 + t;
    int sv[SC_K], dv[SC_K];
    bool ok[SC_K];
#pragma unroll
    for (int k = 0; k < SC_K; ++k) {
      int e = base + k * SC_THREADS;
      ok[k] = e < NE_N;
      int ec = ok[k] ? e : (NE_N - 1);
      sv[k] = esrc[ec];
      dv[k] = edst[ec];
    }
#pragma unroll
    for (int k = 0; k < SC_K; ++k) {
      if (ok[k]) {
        int pos = atomicAdd(&cursor[dv[k]], 1);
        if (pos < ELLW) ell[dv[k] * ELLW + pos] = sv[k];
      }
    }
    return;
  }

  // ---- proj role: h = bf16(x@W^T+b) permuted + a_src = h.att ----
  const int bid = blockIdx.x;
  __shared__ float sh_a[128];
  if (t < 128) sh_a[t] = 0.f;
  __syncthreads();

  const int wave = t >> 6, lane = t & 63;
  const int colhalf = wave & 1, rowhalf = wave >> 1;
  const int row0 = bid * 128 + rowhalf * 64;
  const int lr = lane & 15;
  const int q = lane >> 4;

  bf16x8 bfrag[4][4];
  float bv[4], av[4];
#pragma unroll
  for (int nt = 0; nt < 4; ++nt) {
    int wrow = colhalf * 64 + nt * 16 + lr;
    const float* wp = W + wrow * 128 + q * 8;
#pragma unroll
    for (int kb = 0; kb < 4; ++kb) {
      float4 wa = *(const float4*)(wp + kb * 32);
      float4 wb = *(const float4*)(wp + kb * 32 + 4);
      bfrag[nt][kb] = pack8(wa, wb);
    }
    bv[nt] = bias[wrow];
    av[nt] = att[wrow];
  }

#pragma unroll
  for (int rt = 0; rt < 4; ++rt) {
    int arow = row0 + rt * 16 + lr;
    int rowc = (arow < NI_N) ? arow : (NI_N - 1);
    const float* xp = x + (size_t)rowc * 128 + q * 8;
    bf16x8 afrag[4];
#pragma unroll
    for (int kb = 0; kb < 4; ++kb) {
      float4 xa = *(const float4*)(xp + kb * 32);
      float4 xb = *(const float4*)(xp + kb * 32 + 4);
      afrag[kb] = pack8(xa, xb);
    }
    float part[4] = {0.f, 0.f, 0.f, 0.f};
    f32x4 cc[4];
#pragma unroll
    for (int nt = 0; nt < 4; ++nt) {
      f32x4 c = {0.f, 0.f, 0.f, 0.f};
#pragma unroll
      for (int kb = 0; kb < 4; ++kb)
        c = __builtin_amdgcn_mfma_f32_16x16x32_bf16(afrag[kb], bfrag[nt][kb], c,
                                                    0, 0, 0);
#pragma unroll
      for (int i = 0; i < 4; ++i) {
        float v = c[i] + bv[nt];
        part[i] += v * av[nt];
        c[i] = v;
      }
      cc[nt] = c;
    }
#pragma unroll
    for (int i = 0; i < 4; ++i) {
      int orow = row0 + rt * 16 + q * 4 + i;
      if (orow < NI_N) {
        unsigned u0 = (unsigned)f2bf(cc[0][i]) | ((unsigned)f2bf(cc[1][i]) << 16);
        unsigned u1 = (unsigned)f2bf(cc[2][i]) | ((unsigned)f2bf(cc[3][i]) << 16);
        unsigned int* hp = h32 + (size_t)orow * 64 + colhalf * 32 + lr;
        hp[0] = u0;
        hp[16] = u1;
      }
      float p = part[i];
      p += __shfl_xor(p, 1);
      p += __shfl_xor(p, 2);
      p += __shfl_xor(p, 4);
      p += __shfl_xor(p, 8);
      if (lr == 0)
        atomicAdd(&sh_a[rowhalf * 64 + rt * 16 + q * 4 + i], p);
    }
  }
  __syncthreads();
  if (t < 128) {
    int row = bid * 128 + t;
    if (row < NI_N) a_src[row] = sh_a[t];
  }
}

// ---------------------------------------------------------------------------
// k_agg: r14 proven body (8-wide gather + fused BN-stats tail) + NEW
// PROLOGUE computing a_dst in-place: 32 lanes x float4 = one full x_taste
// row (coalesced), dot with weff (LDS), 5-step shfl_xor reduce within the
// half. All prologue registers are dead before the gather loop (unlike
// r15's failed epilogue). Gather loop + stats tail untouched.
// FAILURE CHECK: if VGPR < 60 / dur > 100us, regalloc flipped -> revert.
// ---------------------------------------------------------------------------
__global__ __launch_bounds__(256) void k_agg(const int* __restrict__ deg,
                                             const int* __restrict__ ell,
                                             const float* __restrict__ a_src,
                                             const float* __restrict__ xt,
                                             const float* __restrict__ wbuf,
                                             const unsigned int* __restrict__ h32,
                                             unsigned int* __restrict__ aggb,
                                             float* __restrict__ accum) {
  const int t = threadIdx.x;
  __shared__ float swe[132];
  if (t < 129) swe[t] = wbuf[t];
  __syncthreads();

  int wv = (blockIdx.x * blockDim.x + t) >> 6;
  int lane = t & 63;
  int half = lane >> 5, l = lane & 31;
  int node = wv * 2 + half;  // exact grid: node < NT_N always
  int n = deg[node];
  n = (n > ELLW) ? ELLW : n;

  // ---- a_dst in-place (was k_main's adst role) ----
  float ad;
  {
    float4 xv = *(const float4*)(xt + (size_t)node * 128 + l * 4);
    float4 wv4 = *(const float4*)(swe + l * 4);
    ad = xv.x * wv4.x + xv.y * wv4.y + xv.z * wv4.z + xv.w * wv4.w;
    ad += __shfl_xor(ad, 1);
    ad += __shfl_xor(ad, 2);
    ad += __shfl_xor(ad, 4);
    ad += __shfl_xor(ad, 8);
    ad += __shfl_xor(ad, 16);
    ad += swe[128];  // beff
  }

  float ax = 0.f, ay = 0.f, bx = 0.f, by = 0.f;
  if (n > 0) {
    int li = (l < n) ? l : (n - 1);
    int sr = ell[node * ELLW + li];
    float al = a_src[sr] + ad;
    al = (al > 0.f) ? al : 0.2f * al;  // leaky_relu 0.2
    float ex = (l < n) ? __expf(al) : 0.f;
    float den = 0.f;
    const int sb = half << 5;
    int n8 = (n + 7) & ~7;
    const uint2* h2 = (const uint2*)h32;
    for (int j = 0; j < n8; j += 8) {
      int s0 = __shfl(sr, sb + j + 0), s1 = __shfl(sr, sb + j + 1);
      int s2 = __shfl(sr, sb + j + 2), s3 = __shfl(sr, sb + j + 3);
      int s4 = __shfl(sr, sb + j + 4), s5 = __shfl(sr, sb + j + 5);
      int s6 = __shfl(sr, sb + j + 6), s7 = __shfl(sr, sb + j + 7);
      float e0 = __shfl(ex, sb + j + 0), e1 = __shfl(ex, sb + j + 1);
      float e2 = __shfl(ex, sb + j + 2), e3 = __shfl(ex, sb + j + 3);
      float e4 = __shfl(ex, sb + j + 4), e5 = __shfl(ex, sb + j + 5);
      float e6 = __shfl(ex, sb + j + 6), e7 = __shfl(ex, sb + j + 7);
      uint2 g0 = h2[s0 * 32 + l];
      uint2 g1 = h2[s1 * 32 + l];
      uint2 g2 = h2[s2 * 32 + l];
      uint2 g3 = h2[s3 * 32 + l];
      uint2 g4 = h2[s4 * 32 + l];
      uint2 g5 = h2[s5 * 32 + l];
      uint2 g6 = h2[s6 * 32 + l];
      uint2 g7 = h2[s7 * 32 + l];
      ax += e0 * bf_lo(g0.x) + e1 * bf_lo(g1.x) + e2 * bf_lo(g2.x) +
            e3 * bf_lo(g3.x) + e4 * bf_lo(g4.x) + e5 * bf_lo(g5.x) +
            e6 * bf_lo(g6.x) + e7 * bf_lo(g7.x);
      ay += e0 * bf_hi(g0.x) + e1 * bf_hi(g1.x) + e2 * bf_hi(g2.x) +
            e3 * bf_hi(g3.x) + e4 * bf_hi(g4.x) + e5 * bf_hi(g5.x) +
            e6 * bf_hi(g6.x) + e7 * bf_hi(g7.x);
      bx += e0 * bf_lo(g0.y) + e1 * bf_lo(g1.y) + e2 * bf_lo(g2.y) +
            e3 * bf_lo(g3.y) + e4 * bf_lo(g4.y) + e5 * bf_lo(g5.y) +
            e6 * bf_lo(g6.y) + e7 * bf_lo(g7.y);
      by += e0 * bf_hi(g0.y) + e1 * bf_hi(g1.y) + e2 * bf_hi(g2.y) +
            e3 * bf_hi(g3.y) + e4 * bf_hi(g4.y) + e5 * bf_hi(g5.y) +
            e6 * bf_hi(g6.y) + e7 * bf_hi(g7.y);
      den += ((e0 + e1) + (e2 + e3)) + ((e4 + e5) + (e6 + e7));
    }
    float inv = 1.f / den;
    ax *= inv; ay *= inv; bx *= inv; by *= inv;
  }
  ax = fmaxf(ax, 0.f);
  ay = fmaxf(ay, 0.f);
  bx = fmaxf(bx, 0.f);
  by = fmaxf(by, 0.f);
  uint2 o;
  o.x = (unsigned)f2bf(ax) | ((unsigned)f2bf(ay) << 16);
  o.y = (unsigned)f2bf(bx) | ((unsigned)f2bf(by) << 16);
  ((uint2*)aggb)[node * 32 + l] = o;

  // ---- fused BN-stats tail (values already in registers) ----
  __shared__ float red[8][32][8];
  int hw = (t >> 6) * 2 + half;  // 0..7: which of the block's 8 nodes
  red[hw][l][0] = ax; red[hw][l][1] = ax * ax;
  red[hw][l][2] = ay; red[hw][l][3] = ay * ay;
  red[hw][l][4] = bx; red[hw][l][5] = bx * bx;
  red[hw][l][6] = by; red[hw][l][7] = by * by;
  __syncthreads();
  {
    int p = t >> 2, slot = t & 3;  // p = uint column idx 0..63
    int pp2 = p >> 1, u = p & 1;   // pp2 = uint2 idx (l), u = x/y half
    float s = 0.f;
#pragma unroll
    for (int gg = 0; gg < 8; ++gg) s += red[gg][pp2][u * 4 + slot];
    atomicAdd(&accum[(blockIdx.x & (ACC_REP - 1)) * 256 + t], s);
  }
}

// ---------------------------------------------------------------------------
// k_consts (1 block): reduce the 128 accum replicas (coalesced; 131KB) and
// compute BN scale/shift in TRUE column space: consts[c]=scale,
// consts[128+c]=shift. Separate dispatch ON PURPOSE (r15: folding this into
// k_agg's last block collapsed its VGPR 80->36 and ran 14x slower).
// ---------------------------------------------------------------------------
__global__ __launch_bounds__(256) void k_consts(const float* __restrict__ accum,
                                                const float* __restrict__ gamma,
                                                const float* __restrict__ beta,
                                                float* __restrict__ consts) {
  __shared__ float fin[256];
  int t = threadIdx.x;
  float s = 0.f;
#pragma unroll 8
  for (int r = 0; r < ACC_REP; ++r) s += accum[r * 256 + t];
  fin[t] = s;
  __syncthreads();
  if (t < 128) {
    int c = t;  // true col handled by this thread
    int ch = c >> 6, rem = c & 63;
    int w = rem >> 5, rem2 = rem & 31;
    int half = rem2 >> 4, lr = rem2 & 15;
    int p = ch * 32 + w * 16 + lr;
    float sum = fin[p * 4 + half * 2];
    float sq = fin[p * 4 + half * 2 + 1];
    float mu = sum * (1.f / NT_N);
    float var = sq * (1.f / NT_N) - mu * mu;
    float sc = gamma[c] * rsqrtf(var + EPS_F);
    consts[c] = sc;
    consts[128 + c] = beta[c] - mu * sc;
  }
}

// ---------------------------------------------------------------------------
// k_norm: uint4-vectorized: read 16B of permuted bf16 agg per lane, BN+ReLU,
// write two float4s in true column order. consts cached in LDS.
// ---------------------------------------------------------------------------
__global__ __launch_bounds__(256) void k_norm(const unsigned int* __restrict__ aggb,
                                              const float* __restrict__ consts,
                                              float* __restrict__ out) {
  __shared__ float sc[256];
  int t = threadIdx.x;
  sc[t] = consts[t];
  __syncthreads();
  int u = blockIdx.x * 256 + t;  // uint4 index over NT_N*16
  if (u >= NT_N * 16) return;
  uint4 v = ((const uint4*)aggb)[u];
  int wid = u >> 4, k = u & 15;
  int p0 = k * 4;
  int c0 = (p0 >> 5) * 64 + ((p0 >> 4) & 1) * 32 + (p0 & 15);
  unsigned vv[4] = {v.x, v.y, v.z, v.w};
  float o0[4], o1[4];
#pragma unroll
  for (int j = 0; j < 4; ++j) {
    int c = c0 + j;
    float lo = bf_lo(vv[j]), hi = bf_hi(vv[j]);
    o0[j] = fmaxf(lo * sc[c] + sc[128 + c], 0.f);
    o1[j] = fmaxf(hi * sc[c + 16] + sc[144 + c], 0.f);
  }
  float* op = out + (size_t)wid * 128 + c0;
  *(float4*)op = make_float4(o0[0], o0[1], o0[2], o0[3]);
  *(float4*)(op + 16) = make_float4(o1[0], o1[1], o1[2], o1[3]);
}

// ---------------------------------------------------------------------------
extern "C" void kernel_launch(void* const* d_in, const int* in_sizes, int n_in,
                              void* d_out, int out_size, void* d_ws, size_t ws_size,
                              hipStream_t stream) {
  const float* x_ing = (const float*)d_in[0];
  const float* x_taste = (const float*)d_in[1];
  const int* edges = (const int*)d_in[2];  // [2][E]
  const float* W_ing = (const float*)d_in[3];
  const float* b_ing = (const float*)d_in[4];
  const float* W_taste = (const float*)d_in[5];
  const float* b_taste = (const float*)d_in[6];
  const float* att_src = (const float*)d_in[7];
  const float* att_dst = (const float*)d_in[8];
  // d_in[9..11] (k_lin_W, k_lin_b, q) unused: beta_sem == 1.0 exactly.
  const float* gamma = (const float*)d_in[12];
  const float* beta = (const float*)d_in[13];
  float* out = (float*)d_out;
  (void)in_sizes; (void)n_in; (void)out_size; (void)ws_size;

  const int* e_src = edges;
  const int* e_dst = edges + NE_N;

  char* ws = (char*)d_ws;
  size_t off = 0;
  auto alloc = [&](size_t bytes) {
    void* p = ws + off;
    off += (bytes + 255) & ~size_t(255);
    return p;
  };
  unsigned int* h32 = (unsigned int*)alloc(sizeof(unsigned int) * NI_N * 64);
  unsigned int* aggb = (unsigned int*)alloc(sizeof(unsigned int) * NT_N * 64);
  float* a_src = (float*)alloc(sizeof(float) * NI_N);
  float* consts = (float*)alloc(sizeof(float) * 256);
  float* wbuf = (float*)alloc(sizeof(float) * 256);
  float* accum = (float*)alloc(sizeof(float) * ACC_REP * 256);
  int* cursor = (int*)alloc(sizeof(int) * NT_N);
  int* ell = (int*)alloc(sizeof(int) * NT_N * ELLW);

  k_pre<<<NB_ZERO + 1, 256, 0, stream>>>(W_taste, b_taste, att_dst, wbuf,
                                         cursor, accum);
  k_main<<<NB_PROJ + NB_SC, 256, 0, stream>>>(
      x_ing, W_ing, b_ing, att_src, h32, a_src, e_src, e_dst, cursor, ell);
  k_agg<<<((NT_N + 1) / 2 * 64 + 255) / 256, 256, 0, stream>>>(
      cursor, ell, a_src, x_taste, wbuf, h32, aggb, accum);
  k_consts<<<1, 256, 0, stream>>>(accum, gamma, beta, consts);
  k_norm<<<(NT_N * 16 + 255) / 256, 256, 0, stream>>>(aggb, consts, out);
}

// Round 18
// 274.616 us; speedup vs baseline: 1.0045x; 1.0045x over previous
//
#include <hip/hip_runtime.h>
#include <hip/hip_bf16.h>

#define HIDDEN 128
#define NI_N 100000
#define NT_N 100000
#define NE_N 800000
#define EPS_F 1e-5f
#define ELLW 32
#define ACC_REP 128           // accum replicas: 12500 agg blocks / 128 ~= 98
                              // same-XCD contenders per address (128 % 8 == 0)

// k_main block layout: [0,NB_PROJ) proj, [NB_PROJ,NB_PROJ+NB_SC) scatter,
// block NB_PROJ+NB_SC = weff (consumed by k_agg next dispatch).
#define NB_PROJ 782
#define NB_SC 512
#define SC_THREADS (NB_SC * 256)
#define SC_K 7                // 512*256*7 >= 800000

typedef __attribute__((ext_vector_type(8))) short bf16x8;
typedef __attribute__((ext_vector_type(4))) float f32x4;

static __device__ __forceinline__ unsigned short f2bf(float f) {
  unsigned u = __float_as_uint(f);
  u += 0x7FFFu + ((u >> 16) & 1u);  // round-to-nearest-even
  return (unsigned short)(u >> 16);
}

static __device__ __forceinline__ bf16x8 pack8(float4 a, float4 b) {
  bf16x8 r;
  r[0] = (short)f2bf(a.x); r[1] = (short)f2bf(a.y);
  r[2] = (short)f2bf(a.z); r[3] = (short)f2bf(a.w);
  r[4] = (short)f2bf(b.x); r[5] = (short)f2bf(b.y);
  r[6] = (short)f2bf(b.z); r[7] = (short)f2bf(b.w);
  return r;
}

static __device__ __forceinline__ float bf_lo(unsigned int h) {
  return __uint_as_float(h << 16);
}
static __device__ __forceinline__ float bf_hi(unsigned int h) {
  return __uint_as_float(h & 0xffff0000u);
}

// permuted-layout column mapping: uint index p holds true cols c0(p) [lo16]
// and c0(p)+16 [hi16], where c0 = (p>>5)*64 + ((p>>4)&1)*32 + (p&15).

// ---------------------------------------------------------------------------
// k_main: proj + scatter + ONE weff block. k_pre deleted: cursor/accum are
// zeroed by hipMemsetAsync; weff (consumed only by the NEXT dispatch,
// k_agg) is computed by the last block here. Avoids r12's per-block weff
// recompute AND r13's separate-dispatch boundary. Proj/scatter bodies
// byte-identical to the r7 proven forms. Kept standalone: proj needs 104
// VGPR (r4/r9/r10: never co-compile with low-VGPR phases, never clamp).
// ---------------------------------------------------------------------------
__global__ __launch_bounds__(256) void k_main(
    const float* __restrict__ x, const float* __restrict__ W,
    const float* __restrict__ bias, const float* __restrict__ att,
    unsigned int* __restrict__ h32, float* __restrict__ a_src,
    const int* __restrict__ esrc, const int* __restrict__ edst,
    int* __restrict__ cursor, int* __restrict__ ell,
    const float* __restrict__ Wt, const float* __restrict__ bt,
    const float* __restrict__ attd, float* __restrict__ wbuf) {
  const int t = threadIdx.x;

  if (blockIdx.x == NB_PROJ + NB_SC) {
    // ---- weff role (1 block): weff = att_dst @ W_taste, beff = att.b ----
    __shared__ float red[128];
    if (t < 128) {
      float s = 0.f;
#pragma unroll 8
      for (int c = 0; c < 128; ++c) s += attd[c] * Wt[c * 128 + t];
      wbuf[t] = s;
      red[t] = attd[t] * bt[t];
    }
    __syncthreads();
    if (t < 64) {
      float v = red[t] + red[t + 64];
      v += __shfl_xor(v, 1);
      v += __shfl_xor(v, 2);
      v += __shfl_xor(v, 4);
      v += __shfl_xor(v, 8);
      v += __shfl_xor(v, 16);
      v += __shfl_xor(v, 32);
      if (t == 0) wbuf[128] = v;
    }
    return;
  }

  if (blockIdx.x >= NB_PROJ) {
    // ---- scatter role: 7 edges per thread, phase-split for MLP ----
    int base = (blockIdx.x - NB_PROJ) * 256 + t;
    int sv[SC_K], dv[SC_K];
    bool ok[SC_K];
#pragma unroll
    for (int k = 0; k < SC_K; ++k) {
      int e = base + k * SC_THREADS;
      ok[k] = e < NE_N;
      int ec = ok[k] ? e : (NE_N - 1);
      sv[k] = esrc[ec];
      dv[k] = edst[ec];
    }
#pragma unroll
    for (int k = 0; k < SC_K; ++k) {
      if (ok[k]) {
        int pos = atomicAdd(&cursor[dv[k]], 1);
        if (pos < ELLW) ell[dv[k] * ELLW + pos] = sv[k];
      }
    }
    return;
  }

  // ---- proj role: h = bf16(x@W^T+b) permuted + a_src = h.att ----
  const int bid = blockIdx.x;
  __shared__ float sh_a[128];
  if (t < 128) sh_a[t] = 0.f;
  __syncthreads();

  const int wave = t >> 6, lane = t & 63;
  const int colhalf = wave & 1, rowhalf = wave >> 1;
  const int row0 = bid * 128 + rowhalf * 64;
  const int lr = lane & 15;
  const int q = lane >> 4;

  bf16x8 bfrag[4][4];
  float bv[4], av[4];
#pragma unroll
  for (int nt = 0; nt < 4; ++nt) {
    int wrow = colhalf * 64 + nt * 16 + lr;
    const float* wp = W + wrow * 128 + q * 8;
#pragma unroll
    for (int kb = 0; kb < 4; ++kb) {
      float4 wa = *(const float4*)(wp + kb * 32);
      float4 wb = *(const float4*)(wp + kb * 32 + 4);
      bfrag[nt][kb] = pack8(wa, wb);
    }
    bv[nt] = bias[wrow];
    av[nt] = att[wrow];
  }

#pragma unroll
  for (int rt = 0; rt < 4; ++rt) {
    int arow = row0 + rt * 16 + lr;
    int rowc = (arow < NI_N) ? arow : (NI_N - 1);
    const float* xp = x + (size_t)rowc * 128 + q * 8;
    bf16x8 afrag[4];
#pragma unroll
    for (int kb = 0; kb < 4; ++kb) {
      float4 xa = *(const float4*)(xp + kb * 32);
      float4 xb = *(const float4*)(xp + kb * 32 + 4);
      afrag[kb] = pack8(xa, xb);
    }
    float part[4] = {0.f, 0.f, 0.f, 0.f};
    f32x4 cc[4];
#pragma unroll
    for (int nt = 0; nt < 4; ++nt) {
      f32x4 c = {0.f, 0.f, 0.f, 0.f};
#pragma unroll
      for (int kb = 0; kb < 4; ++kb)
        c = __builtin_amdgcn_mfma_f32_16x16x32_bf16(afrag[kb], bfrag[nt][kb], c,
                                                    0, 0, 0);
#pragma unroll
      for (int i = 0; i < 4; ++i) {
        float v = c[i] + bv[nt];
        part[i] += v * av[nt];
        c[i] = v;
      }
      cc[nt] = c;
    }
#pragma unroll
    for (int i = 0; i < 4; ++i) {
      int orow = row0 + rt * 16 + q * 4 + i;
      if (orow < NI_N) {
        unsigned u0 = (unsigned)f2bf(cc[0][i]) | ((unsigned)f2bf(cc[1][i]) << 16);
        unsigned u1 = (unsigned)f2bf(cc[2][i]) | ((unsigned)f2bf(cc[3][i]) << 16);
        unsigned int* hp = h32 + (size_t)orow * 64 + colhalf * 32 + lr;
        hp[0] = u0;
        hp[16] = u1;
      }
      float p = part[i];
      p += __shfl_xor(p, 1);
      p += __shfl_xor(p, 2);
      p += __shfl_xor(p, 4);
      p += __shfl_xor(p, 8);
      if (lr == 0)
        atomicAdd(&sh_a[rowhalf * 64 + rt * 16 + q * 4 + i], p);
    }
  }
  __syncthreads();
  if (t < 128) {
    int row = bid * 128 + t;
    if (row < NI_N) a_src[row] = sh_a[t];
  }
}

// ---------------------------------------------------------------------------
// k_agg: r17 proven form, byte-identical (a_dst prologue + 8-wide gather +
// fused BN-stats tail). The gather loop needs its ~80+ VGPR MLP: r15's
// consts-finalize epilogue dropped VGPR to 36 and ran 14x slower. NOTHING
// more gets added to this kernel.
// ---------------------------------------------------------------------------
__global__ __launch_bounds__(256) void k_agg(const int* __restrict__ deg,
                                             const int* __restrict__ ell,
                                             const float* __restrict__ a_src,
                                             const float* __restrict__ xt,
                                             const float* __restrict__ wbuf,
                                             const unsigned int* __restrict__ h32,
                                             unsigned int* __restrict__ aggb,
                                             float* __restrict__ accum) {
  const int t = threadIdx.x;
  __shared__ float swe[132];
  if (t < 129) swe[t] = wbuf[t];
  __syncthreads();

  int wv = (blockIdx.x * blockDim.x + t) >> 6;
  int lane = t & 63;
  int half = lane >> 5, l = lane & 31;
  int node = wv * 2 + half;  // exact grid: node < NT_N always
  int n = deg[node];
  n = (n > ELLW) ? ELLW : n;

  // ---- a_dst in-place (32 lanes x float4 = one x_taste row) ----
  float ad;
  {
    float4 xv = *(const float4*)(xt + (size_t)node * 128 + l * 4);
    float4 wv4 = *(const float4*)(swe + l * 4);
    ad = xv.x * wv4.x + xv.y * wv4.y + xv.z * wv4.z + xv.w * wv4.w;
    ad += __shfl_xor(ad, 1);
    ad += __shfl_xor(ad, 2);
    ad += __shfl_xor(ad, 4);
    ad += __shfl_xor(ad, 8);
    ad += __shfl_xor(ad, 16);
    ad += swe[128];  // beff
  }

  float ax = 0.f, ay = 0.f, bx = 0.f, by = 0.f;
  if (n > 0) {
    int li = (l < n) ? l : (n - 1);
    int sr = ell[node * ELLW + li];
    float al = a_src[sr] + ad;
    al = (al > 0.f) ? al : 0.2f * al;  // leaky_relu 0.2
    float ex = (l < n) ? __expf(al) : 0.f;
    float den = 0.f;
    const int sb = half << 5;
    int n8 = (n + 7) & ~7;
    const uint2* h2 = (const uint2*)h32;
    for (int j = 0; j < n8; j += 8) {
      int s0 = __shfl(sr, sb + j + 0), s1 = __shfl(sr, sb + j + 1);
      int s2 = __shfl(sr, sb + j + 2), s3 = __shfl(sr, sb + j + 3);
      int s4 = __shfl(sr, sb + j + 4), s5 = __shfl(sr, sb + j + 5);
      int s6 = __shfl(sr, sb + j + 6), s7 = __shfl(sr, sb + j + 7);
      float e0 = __shfl(ex, sb + j + 0), e1 = __shfl(ex, sb + j + 1);
      float e2 = __shfl(ex, sb + j + 2), e3 = __shfl(ex, sb + j + 3);
      float e4 = __shfl(ex, sb + j + 4), e5 = __shfl(ex, sb + j + 5);
      float e6 = __shfl(ex, sb + j + 6), e7 = __shfl(ex, sb + j + 7);
      uint2 g0 = h2[s0 * 32 + l];
      uint2 g1 = h2[s1 * 32 + l];
      uint2 g2 = h2[s2 * 32 + l];
      uint2 g3 = h2[s3 * 32 + l];
      uint2 g4 = h2[s4 * 32 + l];
      uint2 g5 = h2[s5 * 32 + l];
      uint2 g6 = h2[s6 * 32 + l];
      uint2 g7 = h2[s7 * 32 + l];
      ax += e0 * bf_lo(g0.x) + e1 * bf_lo(g1.x) + e2 * bf_lo(g2.x) +
            e3 * bf_lo(g3.x) + e4 * bf_lo(g4.x) + e5 * bf_lo(g5.x) +
            e6 * bf_lo(g6.x) + e7 * bf_lo(g7.x);
      ay += e0 * bf_hi(g0.x) + e1 * bf_hi(g1.x) + e2 * bf_hi(g2.x) +
            e3 * bf_hi(g3.x) + e4 * bf_hi(g4.x) + e5 * bf_hi(g5.x) +
            e6 * bf_hi(g6.x) + e7 * bf_hi(g7.x);
      bx += e0 * bf_lo(g0.y) + e1 * bf_lo(g1.y) + e2 * bf_lo(g2.y) +
            e3 * bf_lo(g3.y) + e4 * bf_lo(g4.y) + e5 * bf_lo(g5.y) +
            e6 * bf_lo(g6.y) + e7 * bf_lo(g7.y);
      by += e0 * bf_hi(g0.y) + e1 * bf_hi(g1.y) + e2 * bf_hi(g2.y) +
            e3 * bf_hi(g3.y) + e4 * bf_hi(g4.y) + e5 * bf_hi(g5.y) +
            e6 * bf_hi(g6.y) + e7 * bf_hi(g7.y);
      den += ((e0 + e1) + (e2 + e3)) + ((e4 + e5) + (e6 + e7));
    }
    float inv = 1.f / den;
    ax *= inv; ay *= inv; bx *= inv; by *= inv;
  }
  ax = fmaxf(ax, 0.f);
  ay = fmaxf(ay, 0.f);
  bx = fmaxf(bx, 0.f);
  by = fmaxf(by, 0.f);
  uint2 o;
  o.x = (unsigned)f2bf(ax) | ((unsigned)f2bf(ay) << 16);
  o.y = (unsigned)f2bf(bx) | ((unsigned)f2bf(by) << 16);
  ((uint2*)aggb)[node * 32 + l] = o;

  // ---- fused BN-stats tail (values already in registers) ----
  __shared__ float red[8][32][8];
  int hw = (t >> 6) * 2 + half;  // 0..7: which of the block's 8 nodes
  red[hw][l][0] = ax; red[hw][l][1] = ax * ax;
  red[hw][l][2] = ay; red[hw][l][3] = ay * ay;
  red[hw][l][4] = bx; red[hw][l][5] = bx * bx;
  red[hw][l][6] = by; red[hw][l][7] = by * by;
  __syncthreads();
  {
    int p = t >> 2, slot = t & 3;  // p = uint column idx 0..63
    int pp2 = p >> 1, u = p & 1;   // pp2 = uint2 idx (l), u = x/y half
    float s = 0.f;
#pragma unroll
    for (int gg = 0; gg < 8; ++gg) s += red[gg][pp2][u * 4 + slot];
    atomicAdd(&accum[(blockIdx.x & (ACC_REP - 1)) * 256 + t], s);
  }
}

// ---------------------------------------------------------------------------
// k_consts (1 block): reduce the 128 accum replicas (coalesced; 131KB) and
// compute BN scale/shift in TRUE column space: consts[c]=scale,
// consts[128+c]=shift. Separate dispatch ON PURPOSE (r15: folding this into
// k_agg's last block collapsed its VGPR 80->36 and ran 14x slower).
// ---------------------------------------------------------------------------
__global__ __launch_bounds__(256) void k_consts(const float* __restrict__ accum,
                                                const float* __restrict__ gamma,
                                                const float* __restrict__ beta,
                                                float* __restrict__ consts) {
  __shared__ float fin[256];
  int t = threadIdx.x;
  float s = 0.f;
#pragma unroll 8
  for (int r = 0; r < ACC_REP; ++r) s += accum[r * 256 + t];
  fin[t] = s;
  __syncthreads();
  if (t < 128) {
    int c = t;  // true col handled by this thread
    int ch = c >> 6, rem = c & 63;
    int w = rem >> 5, rem2 = rem & 31;
    int half = rem2 >> 4, lr = rem2 & 15;
    int p = ch * 32 + w * 16 + lr;
    float sum = fin[p * 4 + half * 2];
    float sq = fin[p * 4 + half * 2 + 1];
    float mu = sum * (1.f / NT_N);
    float var = sq * (1.f / NT_N) - mu * mu;
    float sc = gamma[c] * rsqrtf(var + EPS_F);
    consts[c] = sc;
    consts[128 + c] = beta[c] - mu * sc;
  }
}

// ---------------------------------------------------------------------------
// k_norm: uint4-vectorized: read 16B of permuted bf16 agg per lane, BN+ReLU,
// write two float4s in true column order. consts cached in LDS.
// ---------------------------------------------------------------------------
__global__ __launch_bounds__(256) void k_norm(const unsigned int* __restrict__ aggb,
                                              const float* __restrict__ consts,
                                              float* __restrict__ out) {
  __shared__ float sc[256];
  int t = threadIdx.x;
  sc[t] = consts[t];
  __syncthreads();
  int u = blockIdx.x * 256 + t;  // uint4 index over NT_N*16
  if (u >= NT_N * 16) return;
  uint4 v = ((const uint4*)aggb)[u];
  int wid = u >> 4, k = u & 15;
  int p0 = k * 4;
  int c0 = (p0 >> 5) * 64 + ((p0 >> 4) & 1) * 32 + (p0 & 15);
  unsigned vv[4] = {v.x, v.y, v.z, v.w};
  float o0[4], o1[4];
#pragma unroll
  for (int j = 0; j < 4; ++j) {
    int c = c0 + j;
    float lo = bf_lo(vv[j]), hi = bf_hi(vv[j]);
    o0[j] = fmaxf(lo * sc[c] + sc[128 + c], 0.f);
    o1[j] = fmaxf(hi * sc[c + 16] + sc[144 + c], 0.f);
  }
  float* op = out + (size_t)wid * 128 + c0;
  *(float4*)op = make_float4(o0[0], o0[1], o0[2], o0[3]);
  *(float4*)(op + 16) = make_float4(o1[0], o1[1], o1[2], o1[3]);
}

// ---------------------------------------------------------------------------
extern "C" void kernel_launch(void* const* d_in, const int* in_sizes, int n_in,
                              void* d_out, int out_size, void* d_ws, size_t ws_size,
                              hipStream_t stream) {
  const float* x_ing = (const float*)d_in[0];
  const float* x_taste = (const float*)d_in[1];
  const int* edges = (const int*)d_in[2];  // [2][E]
  const float* W_ing = (const float*)d_in[3];
  const float* b_ing = (const float*)d_in[4];
  const float* W_taste = (const float*)d_in[5];
  const float* b_taste = (const float*)d_in[6];
  const float* att_src = (const float*)d_in[7];
  const float* att_dst = (const float*)d_in[8];
  // d_in[9..11] (k_lin_W, k_lin_b, q) unused: beta_sem == 1.0 exactly.
  const float* gamma = (const float*)d_in[12];
  const float* beta = (const float*)d_in[13];
  float* out = (float*)d_out;
  (void)in_sizes; (void)n_in; (void)out_size; (void)ws_size;

  const int* e_src = edges;
  const int* e_dst = edges + NE_N;

  char* ws = (char*)d_ws;
  size_t off = 0;
  auto alloc = [&](size_t bytes) {
    void* p = ws + off;
    off += (bytes + 255) & ~size_t(255);
    return p;
  };
  unsigned int* h32 = (unsigned int*)alloc(sizeof(unsigned int) * NI_N * 64);
  unsigned int* aggb = (unsigned int*)alloc(sizeof(unsigned int) * NT_N * 64);
  float* a_src = (float*)alloc(sizeof(float) * NI_N);
  float* consts = (float*)alloc(sizeof(float) * 256);
  float* wbuf = (float*)alloc(sizeof(float) * 256);
  // --- contiguous zero-region: cursor | accum (single memset) ---
  int* cursor = (int*)alloc(sizeof(int) * NT_N);                // 1600000 B
  float* accum = (float*)alloc(sizeof(float) * ACC_REP * 256);  // 131072 B
  size_t zero_bytes = (size_t)((char*)accum + sizeof(float) * ACC_REP * 256 -
                               (char*)cursor);
  int* ell = (int*)alloc(sizeof(int) * NT_N * ELLW);

  hipMemsetAsync(cursor, 0, zero_bytes, stream);
  k_main<<<NB_PROJ + NB_SC + 1, 256, 0, stream>>>(
      x_ing, W_ing, b_ing, att_src, h32, a_src, e_src, e_dst, cursor, ell,
      W_taste, b_taste, att_dst, wbuf);
  k_agg<<<((NT_N + 1) / 2 * 64 + 255) / 256, 256, 0, stream>>>(
      cursor, ell, a_src, x_taste, wbuf, h32, aggb, accum);
  k_consts<<<1, 256, 0, stream>>>(accum, gamma, beta, consts);
  k_norm<<<(NT_N * 16 + 255) / 256, 256, 0, stream>>>(aggb, consts, out);
}